// Round 1
// baseline (779.481 us; speedup 1.0000x reference)
//
#include <hip/hip_runtime.h>
#include <hip/hip_bf16.h>

#define NHD 16          // NH
#define NKVH 8          // NKV
#define HDIM 256        // HD
#define TSEQ 2048       // T
#define BATCH 2         // B

typedef unsigned int   u32;
typedef unsigned short u16;

typedef __attribute__((ext_vector_type(8))) short bf16x8;
typedef __attribute__((ext_vector_type(4))) float floatx4;

__device__ inline u32 cvt2bf(float lo, float hi) {
  u32 r;
  asm("v_cvt_pk_bf16_f32 %0, %1, %2" : "=v"(r) : "v"(lo), "v"(hi));
  return r;
}
__device__ inline u16 f2bf(float f) {
  union { float f; u32 i; } v; v.f = f;
  u32 r = v.i + 0x7fffu + ((v.i >> 16) & 1u);
  return (u16)(r >> 16);
}
__device__ inline float bf2f(u16 u) {
  union { u32 i; float f; } v; v.i = ((u32)u) << 16; return v.f;
}

// ---------------------------------------------------------------------------
// GEMM: C[M,N] = A[M,K] * B[K,N].  A fp32 (ABF16=0) or bf16 (ABF16=1), B fp32.
// 128x128 tile, BK=64, 4 waves (each 64x64 = 4x4 16x16x32 bf16 MFMA frags).
// LDS: A as [m][64k] bf16, B as Bt [n][64k] bf16, XOR-swizzled 16B chunks.
// EPI 0: fp32 [M][N].  EPI 1: bf16 [b][h][t][d] (head split).  EPI 2: bf16
// [b][h][d][t] (V transposed).
// ---------------------------------------------------------------------------
template<int ABF16, int EPI>
__global__ __launch_bounds__(256, 2) void gemm_k(
    const void* __restrict__ Ap, const float* __restrict__ Bp,
    void* __restrict__ Op, int M, int N, int K, int nheads)
{
  __shared__ u16 As[128 * 64];
  __shared__ u16 Bs[128 * 64];
  const int t = threadIdx.x;
  const int lane = t & 63, wave = t >> 6;
  const int lg = lane >> 4, l15 = lane & 15;
  const int mtiles = M >> 7;
  const int mt = (int)blockIdx.x % mtiles, nt = (int)blockIdx.x / mtiles;
  const int m0 = mt << 7, n0 = nt << 7;
  const int wm = wave & 1, wn = wave >> 1;

  const int am = t >> 1,   akq = (t & 1) << 5;   // A unit: row am, 32 k @ akq
  const int bn = t & 127,  bkq = (t >> 7) << 5;  // B unit: col bn, 32 k @ bkq

  const float* Af = (const float*)Ap + (size_t)(m0 + am) * K + akq;
  const u16*   Ab = (const u16*)Ap   + (size_t)(m0 + am) * K + akq;
  const float* Bg = Bp + (size_t)bkq * N + (n0 + bn);

  float4 avf[8];
  uint4  avb[4];
  float  bv[32];

  auto LOAD = [&](int k0) {
    if (ABF16) {
#pragma unroll
      for (int q = 0; q < 4; ++q) avb[q] = *(const uint4*)(Ab + k0 + q * 8);
    } else {
#pragma unroll
      for (int q = 0; q < 8; ++q) avf[q] = *(const float4*)(Af + k0 + q * 4);
    }
    const float* bp = Bg + (size_t)k0 * N;
#pragma unroll
    for (int j = 0; j < 32; ++j) bv[j] = bp[(size_t)j * N];
  };

  auto STORE_LDS = [&]() {
#pragma unroll
    for (int q = 0; q < 4; ++q) {
      uint4 w;
      if (ABF16) w = avb[q];
      else {
        w.x = cvt2bf(avf[2*q].x,   avf[2*q].y);
        w.y = cvt2bf(avf[2*q].z,   avf[2*q].w);
        w.z = cvt2bf(avf[2*q+1].x, avf[2*q+1].y);
        w.w = cvt2bf(avf[2*q+1].z, avf[2*q+1].w);
      }
      int c = (akq >> 3) + q;
      *(uint4*)((char*)As + am * 128 + ((c ^ (am & 7)) << 4)) = w;
    }
#pragma unroll
    for (int q = 0; q < 4; ++q) {
      uint4 w;
      w.x = cvt2bf(bv[8*q+0], bv[8*q+1]);
      w.y = cvt2bf(bv[8*q+2], bv[8*q+3]);
      w.z = cvt2bf(bv[8*q+4], bv[8*q+5]);
      w.w = cvt2bf(bv[8*q+6], bv[8*q+7]);
      int c = (bkq >> 3) + q;
      *(uint4*)((char*)Bs + bn * 128 + ((c ^ (bn & 7)) << 4)) = w;
    }
  };

  floatx4 acc[4][4];
#pragma unroll
  for (int i = 0; i < 4; ++i)
#pragma unroll
    for (int j = 0; j < 4; ++j) acc[i][j] = (floatx4){0.f, 0.f, 0.f, 0.f};

  LOAD(0);
  const int KT = K >> 6;
  for (int kt = 0; kt < KT; ++kt) {
    __syncthreads();
    STORE_LDS();
    __syncthreads();
    if (kt + 1 < KT) LOAD((kt + 1) << 6);
#pragma unroll
    for (int ks = 0; ks < 2; ++ks) {
      bf16x8 af[4], bfv[4];
      const int c = (ks << 2) + lg;
#pragma unroll
      for (int i = 0; i < 4; ++i) {
        int row = (wm << 6) + (i << 4) + l15;
        af[i] = *(const bf16x8*)((const char*)As + row * 128 + ((c ^ (row & 7)) << 4));
      }
#pragma unroll
      for (int j = 0; j < 4; ++j) {
        int row = (wn << 6) + (j << 4) + l15;
        bfv[j] = *(const bf16x8*)((const char*)Bs + row * 128 + ((c ^ (row & 7)) << 4));
      }
#pragma unroll
      for (int i = 0; i < 4; ++i)
#pragma unroll
        for (int j = 0; j < 4; ++j)
          acc[i][j] = __builtin_amdgcn_mfma_f32_16x16x32_bf16(af[i], bfv[j], acc[i][j], 0, 0, 0);
    }
  }

#pragma unroll
  for (int i = 0; i < 4; ++i) {
#pragma unroll
    for (int j = 0; j < 4; ++j) {
#pragma unroll
      for (int r = 0; r < 4; ++r) {
        int mloc = (wm << 6) + (i << 4) + (lg << 2) + r;
        int nloc = (wn << 6) + (j << 4) + l15;
        int m = m0 + mloc, n = n0 + nloc;
        float v = acc[i][j][r];
        if (EPI == 0) {
          ((float*)Op)[(size_t)m * N + n] = v;
        } else if (EPI == 1) {
          int h = n >> 8, d = n & 255;
          int bb = m >> 11, tt = m & 2047;
          ((u16*)Op)[(((size_t)bb * nheads + h) * TSEQ + tt) * HDIM + d] = f2bf(v);
        } else {
          int h = n >> 8, d = n & 255;
          int bb = m >> 11, tt = m & 2047;
          ((u16*)Op)[(((size_t)bb * nheads + h) * HDIM + d) * TSEQ + tt] = f2bf(v);
        }
      }
    }
  }
}

// ---------------------------------------------------------------------------
// RoPE in-place on [b][h][t][256] bf16: pair (d, d+128), theta = t * base^(-d/128)
// ---------------------------------------------------------------------------
__global__ __launch_bounds__(256) void rope_k(u16* buf) {
  size_t idx = (size_t)blockIdx.x * 256 + threadIdx.x;
  int d = (int)(idx & 127);
  size_t rest = idx >> 7;               // (b*nheads + h)*T + t
  int tt = (int)(rest & (TSEQ - 1));
  float invf = exp2f(-(float)d * 0.103810253f);   // log2(10000)/128
  float th = (float)tt * invf;
  float sn, cs;
  sincosf(th, &sn, &cs);
  size_t base = rest * HDIM;
  float x1 = bf2f(buf[base + d]);
  float x2 = bf2f(buf[base + d + 128]);
  buf[base + d]       = f2bf(x1 * cs - x2 * sn);
  buf[base + d + 128] = f2bf(x2 * cs + x1 * sn);
}

// ---------------------------------------------------------------------------
// Causal flash attention with tanh softcap.  Fixed max = 50 (softcap bound):
// p = exp(50*tanh(z/50) - 50) = exp(-100 / (exp(0.04*z) + 1)),  z = s * 1/16.
// Block = 4 waves, each owning 16 q rows (QBLK=64); KVBLK=64.
// QK^T swapped: S^T = mfma(K_frag, Q_frag) -> lane holds q = lane&15.
// P (bf16) through per-wave LDS -> PV normal: Y = mfma(P, V).
// ---------------------------------------------------------------------------
__global__ __launch_bounds__(256, 2) void attn_k(
    const u16* __restrict__ Q, const u16* __restrict__ Kb,
    const u16* __restrict__ Vt, u16* __restrict__ Y)
{
  __shared__ u16 Ks[64 * 256];    // [s][d], 512B rows, swizzled
  __shared__ u16 Vs[256 * 64];    // [d][s], 128B rows, swizzled
  __shared__ u16 Ps[4 * 16 * 64]; // per-wave [q16][s64], 128B rows, swizzled
  __shared__ float Ls[4][16];
  const int t = threadIdx.x, lane = t & 63, w = t >> 6;
  const int lg = lane >> 4, l15 = lane & 15;
  const int qt = blockIdx.x, h = blockIdx.y, b = blockIdx.z;
  const int hkv = h >> 1;

  const u16* Qg = Q + (((size_t)(b * NHD + h)) * TSEQ + qt * 64 + w * 16 + l15) * HDIM;
  bf16x8 qf[8];
#pragma unroll
  for (int ks = 0; ks < 8; ++ks) qf[ks] = *(const bf16x8*)(Qg + ks * 32 + lg * 8);

  floatx4 accY[16];
#pragma unroll
  for (int i = 0; i < 16; ++i) accY[i] = (floatx4){0.f, 0.f, 0.f, 0.f};
  float rsum = 0.f;

  const u16* Kg = Kb + ((size_t)(b * NKVH + hkv)) * TSEQ * HDIM;  // [s][d]
  const u16* Vg = Vt + ((size_t)(b * NKVH + hkv)) * HDIM * TSEQ;  // [d][s]

  const int krow = t >> 2, kseg = (t & 3) << 6;
  const int qglob = qt * 64 + w * 16 + l15;

  for (int st = 0; st <= qt; ++st) {
    __syncthreads();
    {
      uint4 kv[8];
#pragma unroll
      for (int q = 0; q < 8; ++q)
        kv[q] = *(const uint4*)(Kg + (size_t)(st * 64 + krow) * HDIM + kseg + q * 8);
#pragma unroll
      for (int q = 0; q < 8; ++q) {
        int c = (kseg >> 3) + q;
        *(uint4*)((char*)Ks + krow * 512 + ((c ^ (krow & 7)) << 4)) = kv[q];
      }
      uint4 vv[8];
#pragma unroll
      for (int q = 0; q < 8; ++q)
        vv[q] = *(const uint4*)(Vg + (size_t)t * TSEQ + st * 64 + q * 8);
#pragma unroll
      for (int q = 0; q < 8; ++q)
        *(uint4*)((char*)Vs + t * 128 + ((q ^ (t & 7)) << 4)) = vv[q];
    }
    __syncthreads();

    // --- QK^T (swapped) + softcap + causal + P write ---
#pragma unroll
    for (int stile = 0; stile < 4; ++stile) {
      floatx4 sa = (floatx4){0.f, 0.f, 0.f, 0.f};
#pragma unroll
      for (int ks = 0; ks < 8; ++ks) {
        int row = (stile << 4) + l15;
        int c = (ks << 2) + lg;
        bf16x8 kf = *(const bf16x8*)((const char*)Ks + row * 512 + ((c ^ (row & 7)) << 4));
        sa = __builtin_amdgcn_mfma_f32_16x16x32_bf16(kf, qf[ks], sa, 0, 0, 0);
      }
      int sbase = st * 64 + (stile << 4) + (lg << 2);
      float p[4];
#pragma unroll
      for (int r = 0; r < 4; ++r) {
        float z = sa[r] * 0.0625f;
        float u = __expf(z * 0.04f);
        float pv = __expf(-100.0f / (u + 1.0f));
        pv = (sbase + r <= qglob) ? pv : 0.0f;
        p[r] = pv;
        rsum += pv;
      }
      uint2 pw;
      pw.x = cvt2bf(p[0], p[1]);
      pw.y = cvt2bf(p[2], p[3]);
      int o = (stile << 5) + (lg << 3);
      int chunk = o >> 4;
      *(uint2*)((char*)Ps + (w << 11) + l15 * 128 + ((chunk ^ (l15 & 7)) << 4) + (o & 15)) = pw;
    }
    // --- PV ---
#pragma unroll
    for (int ss = 0; ss < 2; ++ss) {
      int c = (ss << 2) + lg;
      bf16x8 pf = *(const bf16x8*)((const char*)Ps + (w << 11) + l15 * 128 + ((c ^ (l15 & 7)) << 4));
#pragma unroll
      for (int dt = 0; dt < 16; ++dt) {
        int row = (dt << 4) + l15;
        bf16x8 vf = *(const bf16x8*)((const char*)Vs + row * 128 + ((c ^ (row & 7)) << 4));
        accY[dt] = __builtin_amdgcn_mfma_f32_16x16x32_bf16(pf, vf, accY[dt], 0, 0, 0);
      }
    }
  }

  // denominator: full row sums for q = l15, broadcast via LDS to (lg*4+r) layout
  rsum += __shfl_xor(rsum, 16);
  rsum += __shfl_xor(rsum, 32);
  if (lane < 16) Ls[w][l15] = rsum;
  __syncthreads();
  float inv[4];
#pragma unroll
  for (int r = 0; r < 4; ++r) inv[r] = 1.0f / Ls[w][(lg << 2) + r];

  u16* Yg = Y + ((size_t)(b * TSEQ + qt * 64 + w * 16)) * (NHD * HDIM) + h * HDIM;
#pragma unroll
  for (int dt = 0; dt < 16; ++dt)
#pragma unroll
    for (int r = 0; r < 4; ++r)
      Yg[(size_t)((lg << 2) + r) * (NHD * HDIM) + (dt << 4) + l15] =
          f2bf(accY[dt][r] * inv[r]);
}

// ---------------------------------------------------------------------------
extern "C" void kernel_launch(void* const* d_in, const int* in_sizes, int n_in,
                              void* d_out, int out_size, void* d_ws, size_t ws_size,
                              hipStream_t stream) {
  const float* X  = (const float*)d_in[0];
  const float* Wq = (const float*)d_in[1];
  const float* Wk = (const float*)d_in[2];
  const float* Wv = (const float*)d_in[3];
  const float* Wo = (const float*)d_in[4];
  float* out = (float*)d_out;

  u16* ws   = (u16*)d_ws;
  u16* Qb   = ws;                      // [B][NH][T][HD]    16,777,216
  u16* Kbuf = ws + 16777216;           // [B][NKV][T][HD]    8,388,608
  u16* Vtb  = ws + 25165824;           // [B][NKV][HD][T]    8,388,608
  u16* Yb   = ws + 33554432;           // [B*T][NH*HD]      16,777,216

  dim3 blk(256);
  // projections (M=4096, K=2048)
  gemm_k<0, 1><<<dim3(32 * 32), blk, 0, stream>>>(X, Wq, Qb,   4096, 4096, 2048, NHD);
  gemm_k<0, 1><<<dim3(32 * 16), blk, 0, stream>>>(X, Wk, Kbuf, 4096, 2048, 2048, NKVH);
  gemm_k<0, 2><<<dim3(32 * 16), blk, 0, stream>>>(X, Wv, Vtb,  4096, 2048, 2048, NKVH);
  // RoPE (in-place)
  rope_k<<<dim3((BATCH * NHD  * TSEQ * 128) / 256), blk, 0, stream>>>(Qb);
  rope_k<<<dim3((BATCH * NKVH * TSEQ * 128) / 256), blk, 0, stream>>>(Kbuf);
  // attention
  attn_k<<<dim3(TSEQ / 64, NHD, BATCH), blk, 0, stream>>>(Qb, Kbuf, Vtb, Yb);
  // output projection (M=4096, N=2048, K=4096) -> fp32 out
  gemm_k<1, 0><<<dim3(32 * 16), blk, 0, stream>>>(Yb, Wo, out, 4096, 2048, 4096, 0);
}